// Round 3
// baseline (770.892 us; speedup 1.0000x reference)
//
#include <hip/hip_runtime.h>
#include <hip/hip_bf16.h>

#define NN 16384
#define TT 4
#define HH 64
#define NT (NN * TT)
#define NEG_SLOPE 0.2f
#define LN_EPS 1e-5f

using bf16 = __hip_bfloat16;

// ---------------- CSR build ----------------

__global__ void zero_kernel(int* __restrict__ a, int n) {
    int i = blockIdx.x * blockDim.x + threadIdx.x;
    if (i < n) a[i] = 0;
}

__global__ void hist_kernel(const int* __restrict__ dst, int* __restrict__ cnt, int E) {
    int e = blockIdx.x * blockDim.x + threadIdx.x;
    if (e < E) atomicAdd(&cnt[dst[e]], 1);
}

// single block, 1024 threads, 16 elems/thread: exclusive scan of cnt[0..NN) -> rp, cur
__global__ __launch_bounds__(1024) void scan_kernel(const int* __restrict__ cnt,
                                                    int* __restrict__ rp,
                                                    int* __restrict__ cur) {
    __shared__ int part[1024];
    int tid = threadIdx.x;
    int base = tid * 16;
    int local[16];
    int sum = 0;
#pragma unroll
    for (int i = 0; i < 16; i++) { local[i] = cnt[base + i]; sum += local[i]; }
    part[tid] = sum;
    __syncthreads();
    for (int off = 1; off < 1024; off <<= 1) {
        int v = (tid >= off) ? part[tid - off] : 0;
        __syncthreads();
        part[tid] += v;
        __syncthreads();
    }
    int run = (tid == 0) ? 0 : part[tid - 1];
#pragma unroll
    for (int i = 0; i < 16; i++) {
        rp[base + i] = run;
        cur[base + i] = run;
        run += local[i];
    }
    if (tid == 1023) rp[NN] = run;
}

__global__ void scatter_kernel(const int* __restrict__ src, const int* __restrict__ dst,
                               int* __restrict__ cur, int* __restrict__ col, int E) {
    int e = blockIdx.x * blockDim.x + threadIdx.x;
    if (e < E) {
        int d = dst[e];
        int pos = atomicAdd(&cur[d], 1);
        col[pos] = src[e];
    }
}

// ---------------- per-node linear transform: h = x*W, s = lrelu(h . a) --------
// one wave per row (row = n*T + t); 16 rows per wave, 4 waves per block.
// x broadcast via __shfl (readlane) -- no LDS, no barriers.

__global__ __launch_bounds__(256) void transform_kernel(const float* __restrict__ x,
                                                        const float* __restrict__ W,
                                                        const float* __restrict__ a,
                                                        bf16* __restrict__ h,
                                                        float* __restrict__ s) {
    const int lane = threadIdx.x & 63;
    const int wv = threadIdx.x >> 6;
    float Wreg[64];
#pragma unroll
    for (int k = 0; k < 64; k++) Wreg[k] = W[k * 64 + lane];
    const float av = a[lane];
    const int row0 = blockIdx.x * 64 + wv * 16;
    for (int it = 0; it < 16; it++) {
        const int row = row0 + it;
        const float xv = x[(long)row * 64 + lane];
        float acc = 0.f;
#pragma unroll
        for (int k = 0; k < 64; k++) {
            acc = fmaf(__shfl(xv, k, 64), Wreg[k], acc);
        }
        h[(long)row * 64 + lane] = __float2bfloat16(acc);
        float v = acc * av;
#pragma unroll
        for (int off = 32; off > 0; off >>= 1) v += __shfl_xor(v, off, 64);
        if (lane == 0) {
            // fold LeakyReLU into the per-node score (elementwise on scalar logit)
            s[row] = (v > 0.f) ? v : NEG_SLOPE * v;
        }
    }
}

// ---------------- attention aggregation ----------------

__device__ __forceinline__ float gather_msg(const bf16* __restrict__ h,
                                            const float* __restrict__ s,
                                            const int* __restrict__ rp,
                                            const int* __restrict__ col,
                                            int n, int t, int lane) {
    int beg = rp[n], end = rp[n + 1];
    float m = -INFINITY;
    for (int j = beg; j < end; j++) {
        int src = col[j];
        float l = s[src * TT + t];
        if (l > m) m = l;
    }
    float den = 0.f, acc = 0.f;
    for (int j = beg; j < end; j++) {
        int src = col[j];
        float l = s[src * TT + t];
        float e = __expf(l - m);
        den += e;
        acc += e * __bfloat162float(h[((long)src * TT + t) * HH + lane]);
    }
    return (end > beg) ? acc / den : 0.f;
}

__global__ __launch_bounds__(256) void aggregate_kernel(
    const float* __restrict__ x,
    const bf16* __restrict__ h_s, const float* __restrict__ s_s,
    const int* __restrict__ rp_s, const int* __restrict__ col_s,
    const bf16* __restrict__ h_f, const float* __restrict__ s_f,
    const int* __restrict__ rp_f, const int* __restrict__ col_f,
    const float* __restrict__ g, const float* __restrict__ b,
    float* __restrict__ out) {
    const int n = blockIdx.x;
    const int t = threadIdx.x >> 6;
    const int lane = threadIdx.x & 63;

    float msg_s = gather_msg(h_s, s_s, rp_s, col_s, n, t, lane);
    float msg_f = gather_msg(h_f, s_f, rp_f, col_f, n, t, lane);

    long idx = ((long)n * TT + t) * HH + lane;
    float val = x[idx] + 0.5f * (msg_s + msg_f);

    float mu = val;
#pragma unroll
    for (int off = 32; off > 0; off >>= 1) mu += __shfl_xor(mu, off, 64);
    mu *= (1.f / 64.f);
    float dv = val - mu;
    float var = dv * dv;
#pragma unroll
    for (int off = 32; off > 0; off >>= 1) var += __shfl_xor(var, off, 64);
    var *= (1.f / 64.f);
    float y = dv * rsqrtf(var + LN_EPS) * g[lane] + b[lane];
    out[idx] = y;
}

// ---------------- launch ----------------

extern "C" void kernel_launch(void* const* d_in, const int* in_sizes, int n_in,
                              void* d_out, int out_size, void* d_ws, size_t ws_size,
                              hipStream_t stream) {
    const float* pred = (const float*)d_in[0];
    const int* ei_s = (const int*)d_in[1];
    const int* ei_f = (const int*)d_in[2];
    const float* W0s = (const float*)d_in[3];
    const float* a0s = (const float*)d_in[4];
    const float* W0f = (const float*)d_in[5];
    const float* a0f = (const float*)d_in[6];
    const float* g0  = (const float*)d_in[7];
    const float* b0  = (const float*)d_in[8];
    const float* W1s = (const float*)d_in[9];
    const float* a1s = (const float*)d_in[10];
    const float* W1f = (const float*)d_in[11];
    const float* a1f = (const float*)d_in[12];
    const float* g1  = (const float*)d_in[13];
    const float* b1  = (const float*)d_in[14];
    const int E = in_sizes[1] / 2;  // 262144

    // workspace bump allocator (total ~37 MB)
    char* ws = (char*)d_ws;
    auto alloc = [&](size_t bytes) {
        char* p = ws;
        ws += (bytes + 255) & ~(size_t)255;
        return p;
    };
    int* cnt_s = (int*)alloc(NN * sizeof(int));
    int* cnt_f = (int*)alloc(NN * sizeof(int));
    int* rp_s  = (int*)alloc((NN + 1) * sizeof(int));
    int* rp_f  = (int*)alloc((NN + 1) * sizeof(int));
    int* cur_s = (int*)alloc(NN * sizeof(int));
    int* cur_f = (int*)alloc(NN * sizeof(int));
    int* col_s = (int*)alloc((size_t)E * sizeof(int));
    int* col_f = (int*)alloc((size_t)E * sizeof(int));
    bf16* h_s  = (bf16*)alloc((size_t)NT * HH * sizeof(bf16));
    bf16* h_f  = (bf16*)alloc((size_t)NT * HH * sizeof(bf16));
    float* s_s = (float*)alloc((size_t)NT * sizeof(float));
    float* s_f = (float*)alloc((size_t)NT * sizeof(float));
    float* x_mid = (float*)alloc((size_t)NT * HH * sizeof(float));

    const int EB = (E + 255) / 256;

    // CSR build (both edge sets)
    zero_kernel<<<NN / 256, 256, 0, stream>>>(cnt_s, NN);
    zero_kernel<<<NN / 256, 256, 0, stream>>>(cnt_f, NN);
    hist_kernel<<<EB, 256, 0, stream>>>(ei_s + E, cnt_s, E);
    hist_kernel<<<EB, 256, 0, stream>>>(ei_f + E, cnt_f, E);
    scan_kernel<<<1, 1024, 0, stream>>>(cnt_s, rp_s, cur_s);
    scan_kernel<<<1, 1024, 0, stream>>>(cnt_f, rp_f, cur_f);
    scatter_kernel<<<EB, 256, 0, stream>>>(ei_s, ei_s + E, cur_s, col_s, E);
    scatter_kernel<<<EB, 256, 0, stream>>>(ei_f, ei_f + E, cur_f, col_f, E);

    // layer 0
    transform_kernel<<<NT / 64, 256, 0, stream>>>(pred, W0s, a0s, h_s, s_s);
    transform_kernel<<<NT / 64, 256, 0, stream>>>(pred, W0f, a0f, h_f, s_f);
    aggregate_kernel<<<NN, 256, 0, stream>>>(
        pred, h_s, s_s, rp_s, col_s, h_f, s_f, rp_f, col_f, g0, b0, x_mid);

    // layer 1
    transform_kernel<<<NT / 64, 256, 0, stream>>>(x_mid, W1s, a1s, h_s, s_s);
    transform_kernel<<<NT / 64, 256, 0, stream>>>(x_mid, W1f, a1f, h_f, s_f);
    aggregate_kernel<<<NN, 256, 0, stream>>>(
        x_mid, h_s, s_s, rp_s, col_s, h_f, s_f, rp_f, col_f, g1, b1, (float*)d_out);
}

// Round 4
// 356.616 us; speedup vs baseline: 2.1617x; 2.1617x over previous
//
#include <hip/hip_runtime.h>
#include <hip/hip_bf16.h>

#define NN 16384
#define TT 4
#define HH 64
#define NT (NN * TT)
#define NEG_SLOPE 0.2f
#define LN_EPS 1e-5f

using bf16 = __hip_bfloat16;

__device__ __forceinline__ float bf2f(unsigned short u) {
    return __uint_as_float((unsigned)u << 16);
}

// ---------------- CSR build (both edge sets fused) ----------------

__global__ void zero_kernel(int* __restrict__ a, int n) {
    int i = blockIdx.x * blockDim.x + threadIdx.x;
    if (i < n) a[i] = 0;
}

// grid 2*EB: first half -> set s, second half -> set f (cnt2 = [2*NN])
__global__ void hist2_kernel(const int* __restrict__ dst_s, const int* __restrict__ dst_f,
                             int* __restrict__ cnt2, int E) {
    int e = blockIdx.x * blockDim.x + threadIdx.x;
    if (e < E) {
        atomicAdd(&cnt2[dst_s[e]], 1);
    } else {
        e -= E;
        if (e < E) atomicAdd(&cnt2[NN + dst_f[e]], 1);
    }
}

// grid 2 blocks x 1024 threads, 16 elems/thread: exclusive scan per set
__global__ __launch_bounds__(1024) void scan2_kernel(const int* __restrict__ cnt2,
                                                     int* __restrict__ rp2,
                                                     int* __restrict__ cur2) {
    __shared__ int part[1024];
    const int set = blockIdx.x;
    const int* cnt = cnt2 + set * NN;
    int* rp = rp2 + set * (NN + 1);
    int* cur = cur2 + set * NN;
    int tid = threadIdx.x;
    int base = tid * 16;
    int local[16];
    int sum = 0;
#pragma unroll
    for (int i = 0; i < 16; i++) { local[i] = cnt[base + i]; sum += local[i]; }
    part[tid] = sum;
    __syncthreads();
    for (int off = 1; off < 1024; off <<= 1) {
        int v = (tid >= off) ? part[tid - off] : 0;
        __syncthreads();
        part[tid] += v;
        __syncthreads();
    }
    int run = (tid == 0) ? 0 : part[tid - 1];
#pragma unroll
    for (int i = 0; i < 16; i++) {
        rp[base + i] = run;
        cur[base + i] = run;
        run += local[i];
    }
    if (tid == 1023) rp[NN] = run;
}

// grid 2*EB: col2 = [2*E], set f at offset E
__global__ void scatter2_kernel(const int* __restrict__ ei_s, const int* __restrict__ ei_f,
                                int* __restrict__ cur2, int* __restrict__ col2, int E) {
    int e = blockIdx.x * blockDim.x + threadIdx.x;
    if (e < E) {
        int d = ei_s[E + e];
        int pos = atomicAdd(&cur2[d], 1);
        col2[pos] = ei_s[e];
    } else {
        e -= E;
        if (e < E) {
            int d = ei_f[E + e];
            int pos = atomicAdd(&cur2[NN + d], 1);
            col2[E + pos] = ei_f[e];
        }
    }
}

// ------- fused dual transform: h_s = x*Ws, h_f = x*Wf, scores with lrelu ------
// one wave per row (row = n*T + t); 16 rows per wave; x broadcast via __shfl.

__global__ __launch_bounds__(256) void transform2_kernel(
    const float* __restrict__ x,
    const float* __restrict__ Ws, const float* __restrict__ as_,
    const float* __restrict__ Wf, const float* __restrict__ af,
    bf16* __restrict__ h_s, float* __restrict__ sc_s,
    bf16* __restrict__ h_f, float* __restrict__ sc_f) {
    const int lane = threadIdx.x & 63;
    const int wv = threadIdx.x >> 6;
    float Wsreg[64], Wfreg[64];
#pragma unroll
    for (int k = 0; k < 64; k++) Wsreg[k] = Ws[k * 64 + lane];
#pragma unroll
    for (int k = 0; k < 64; k++) Wfreg[k] = Wf[k * 64 + lane];
    const float avs = as_[lane];
    const float avf = af[lane];
    const int row0 = blockIdx.x * 64 + wv * 16;
    for (int it = 0; it < 16; it++) {
        const int row = row0 + it;
        const float xv = x[(long)row * 64 + lane];
        float accs = 0.f, accf = 0.f;
#pragma unroll
        for (int k = 0; k < 64; k++) {
            float xk = __shfl(xv, k, 64);
            accs = fmaf(xk, Wsreg[k], accs);
            accf = fmaf(xk, Wfreg[k], accf);
        }
        h_s[(long)row * 64 + lane] = __float2bfloat16(accs);
        h_f[(long)row * 64 + lane] = __float2bfloat16(accf);
        float vs = accs * avs, vf = accf * avf;
#pragma unroll
        for (int off = 32; off > 0; off >>= 1) {
            vs += __shfl_xor(vs, off, 64);
            vf += __shfl_xor(vf, off, 64);
        }
        if (lane == 0) {
            sc_s[row] = (vs > 0.f) ? vs : NEG_SLOPE * vs;  // LeakyReLU folded into score
            sc_f[row] = (vf > 0.f) ? vf : NEG_SLOPE * vf;
        }
    }
}

// ---------------- attention aggregation ----------------
// wave per node; lane: t = lane>>4, channels 4*(lane&15)..+3.
// single-pass softmax (logits are O(+-8): exp cannot overflow in f32;
// exp(l)/sum(exp(l)) == max-subtracted form mathematically).

__device__ __forceinline__ void agg_set(const ushort4* __restrict__ h4,
                                        const float* __restrict__ sc,
                                        const int* __restrict__ rp,
                                        const int* __restrict__ col,
                                        int n, int t, int lane, float4& msg) {
    const int beg = rp[n], end = rp[n + 1];
    float den = 0.f;
    float ax = 0.f, ay = 0.f, az = 0.f, aw = 0.f;
    int j = beg;
    for (; j + 4 <= end; j += 4) {
        // issue all 12 loads before any use (MLP)
        int s0 = col[j], s1 = col[j + 1], s2 = col[j + 2], s3 = col[j + 3];
        float l0 = sc[s0 * 4 + t], l1 = sc[s1 * 4 + t],
              l2 = sc[s2 * 4 + t], l3 = sc[s3 * 4 + t];
        ushort4 h0 = h4[s0 * 64 + lane], h1 = h4[s1 * 64 + lane],
                h2 = h4[s2 * 64 + lane], h3 = h4[s3 * 64 + lane];
        float e0 = __expf(l0), e1 = __expf(l1), e2 = __expf(l2), e3 = __expf(l3);
        den += (e0 + e1) + (e2 + e3);
        ax = fmaf(e0, bf2f(h0.x), ax); ay = fmaf(e0, bf2f(h0.y), ay);
        az = fmaf(e0, bf2f(h0.z), az); aw = fmaf(e0, bf2f(h0.w), aw);
        ax = fmaf(e1, bf2f(h1.x), ax); ay = fmaf(e1, bf2f(h1.y), ay);
        az = fmaf(e1, bf2f(h1.z), az); aw = fmaf(e1, bf2f(h1.w), aw);
        ax = fmaf(e2, bf2f(h2.x), ax); ay = fmaf(e2, bf2f(h2.y), ay);
        az = fmaf(e2, bf2f(h2.z), az); aw = fmaf(e2, bf2f(h2.w), aw);
        ax = fmaf(e3, bf2f(h3.x), ax); ay = fmaf(e3, bf2f(h3.y), ay);
        az = fmaf(e3, bf2f(h3.z), az); aw = fmaf(e3, bf2f(h3.w), aw);
    }
    for (; j < end; j++) {
        int s0 = col[j];
        float l0 = sc[s0 * 4 + t];
        ushort4 h0 = h4[s0 * 64 + lane];
        float e0 = __expf(l0);
        den += e0;
        ax = fmaf(e0, bf2f(h0.x), ax); ay = fmaf(e0, bf2f(h0.y), ay);
        az = fmaf(e0, bf2f(h0.z), az); aw = fmaf(e0, bf2f(h0.w), aw);
    }
    if (end > beg) {
        float r = 1.f / den;
        msg.x = ax * r; msg.y = ay * r; msg.z = az * r; msg.w = aw * r;
    } else {
        msg.x = msg.y = msg.z = msg.w = 0.f;
    }
}

__global__ __launch_bounds__(256) void aggregate_kernel(
    const float4* __restrict__ x4,
    const ushort4* __restrict__ hs4, const float* __restrict__ scs,
    const int* __restrict__ rps, const int* __restrict__ cols,
    const ushort4* __restrict__ hf4, const float* __restrict__ scf,
    const int* __restrict__ rpf, const int* __restrict__ colf,
    const float4* __restrict__ g4, const float4* __restrict__ b4,
    float4* __restrict__ out4) {
    const int wv = threadIdx.x >> 6;
    const int lane = threadIdx.x & 63;
    const int n = blockIdx.x * 4 + wv;
    const int t = lane >> 4;
    const int ci = lane & 15;

    float4 xv = x4[n * 64 + lane];  // x[n][t][4*ci..+3]

    float4 ms, mf;
    agg_set(hs4, scs, rps, cols, n, t, lane, ms);
    agg_set(hf4, scf, rpf, colf, n, t, lane, mf);

    float v0 = xv.x + 0.5f * (ms.x + mf.x);
    float v1 = xv.y + 0.5f * (ms.y + mf.y);
    float v2 = xv.z + 0.5f * (ms.z + mf.z);
    float v3 = xv.w + 0.5f * (ms.w + mf.w);

    // LayerNorm over H=64: 16-lane group (same t), 4 values/lane
    float sum = (v0 + v1) + (v2 + v3);
#pragma unroll
    for (int off = 1; off < 16; off <<= 1) sum += __shfl_xor(sum, off, 64);
    float mu = sum * (1.f / 64.f);
    float d0 = v0 - mu, d1 = v1 - mu, d2 = v2 - mu, d3 = v3 - mu;
    float var = (d0 * d0 + d1 * d1) + (d2 * d2 + d3 * d3);
#pragma unroll
    for (int off = 1; off < 16; off <<= 1) var += __shfl_xor(var, off, 64);
    var *= (1.f / 64.f);
    float inv = rsqrtf(var + LN_EPS);
    float4 gv = g4[ci], bv = b4[ci];
    float4 o;
    o.x = d0 * inv * gv.x + bv.x;
    o.y = d1 * inv * gv.y + bv.y;
    o.z = d2 * inv * gv.z + bv.z;
    o.w = d3 * inv * gv.w + bv.w;
    out4[n * 64 + lane] = o;
}

// ---------------- launch ----------------

extern "C" void kernel_launch(void* const* d_in, const int* in_sizes, int n_in,
                              void* d_out, int out_size, void* d_ws, size_t ws_size,
                              hipStream_t stream) {
    const float* pred = (const float*)d_in[0];
    const int* ei_s = (const int*)d_in[1];
    const int* ei_f = (const int*)d_in[2];
    const float* W0s = (const float*)d_in[3];
    const float* a0s = (const float*)d_in[4];
    const float* W0f = (const float*)d_in[5];
    const float* a0f = (const float*)d_in[6];
    const float* g0  = (const float*)d_in[7];
    const float* b0  = (const float*)d_in[8];
    const float* W1s = (const float*)d_in[9];
    const float* a1s = (const float*)d_in[10];
    const float* W1f = (const float*)d_in[11];
    const float* a1f = (const float*)d_in[12];
    const float* g1  = (const float*)d_in[13];
    const float* b1  = (const float*)d_in[14];
    const int E = in_sizes[1] / 2;  // 262144

    // workspace bump allocator (~37 MB)
    char* ws = (char*)d_ws;
    auto alloc = [&](size_t bytes) {
        char* p = ws;
        ws += (bytes + 255) & ~(size_t)255;
        return p;
    };
    int* cnt2 = (int*)alloc((size_t)2 * NN * sizeof(int));
    int* rp2  = (int*)alloc((size_t)2 * (NN + 1) * sizeof(int));
    int* cur2 = (int*)alloc((size_t)2 * NN * sizeof(int));
    int* col2 = (int*)alloc((size_t)2 * E * sizeof(int));
    bf16* h_s = (bf16*)alloc((size_t)NT * HH * sizeof(bf16));
    bf16* h_f = (bf16*)alloc((size_t)NT * HH * sizeof(bf16));
    float* sc_s = (float*)alloc((size_t)NT * sizeof(float));
    float* sc_f = (float*)alloc((size_t)NT * sizeof(float));
    float* x_mid = (float*)alloc((size_t)NT * HH * sizeof(float));

    const int* rp_s = rp2;
    const int* rp_f = rp2 + (NN + 1);
    const int* col_s = col2;
    const int* col_f = col2 + E;

    const int EB = (E + 255) / 256;

    // CSR build (both edge sets in each launch)
    zero_kernel<<<(2 * NN) / 256, 256, 0, stream>>>(cnt2, 2 * NN);
    hist2_kernel<<<2 * EB, 256, 0, stream>>>(ei_s + E, ei_f + E, cnt2, E);
    scan2_kernel<<<2, 1024, 0, stream>>>(cnt2, rp2, cur2);
    scatter2_kernel<<<2 * EB, 256, 0, stream>>>(ei_s, ei_f, cur2, col2, E);

    // layer 0
    transform2_kernel<<<NT / 64, 256, 0, stream>>>(pred, W0s, a0s, W0f, a0f,
                                                   h_s, sc_s, h_f, sc_f);
    aggregate_kernel<<<NN / 4, 256, 0, stream>>>(
        (const float4*)pred, (const ushort4*)h_s, sc_s, rp_s, col_s,
        (const ushort4*)h_f, sc_f, rp_f, col_f,
        (const float4*)g0, (const float4*)b0, (float4*)x_mid);

    // layer 1
    transform2_kernel<<<NT / 64, 256, 0, stream>>>(x_mid, W1s, a1s, W1f, a1f,
                                                   h_s, sc_s, h_f, sc_f);
    aggregate_kernel<<<NN / 4, 256, 0, stream>>>(
        (const float4*)x_mid, (const ushort4*)h_s, sc_s, rp_s, col_s,
        (const ushort4*)h_f, sc_f, rp_f, col_f,
        (const float4*)g1, (const float4*)b1, (float4*)d_out);
}